// Round 6
// baseline (321.187 us; speedup 1.0000x reference)
//
#include <hip/hip_runtime.h>
#include <stdint.h>

#define Bq 8
#define Mq 1024
#define Hq 512
#define NHq 8
#define Dq 64
#define SPANq 1024
#define MKq 2048
#define PR2 168   // attn P/pos row stride (ushorts); 160 used

typedef __bf16 bf16x8 __attribute__((ext_vector_type(8)));
typedef _Float16 f16x8 __attribute__((ext_vector_type(8)));
typedef float f32x4 __attribute__((ext_vector_type(4)));
typedef unsigned short ushort8 __attribute__((ext_vector_type(8)));
typedef unsigned int uint2v __attribute__((ext_vector_type(2)));

static __device__ __forceinline__ unsigned short f2bf(float f) {
  union { float f; unsigned u; } x; x.f = f;
  unsigned r = x.u + 0x7FFFu + ((x.u >> 16) & 1u);
  return (unsigned short)(r >> 16);
}

static __device__ __forceinline__ unsigned pk_f16(float a, float b) {
  return __builtin_bit_cast(unsigned, __builtin_amdgcn_cvt_pkrtz(a, b));
}

static __device__ __forceinline__ f32x4 mfma_bf16(bf16x8 a, bf16x8 b, f32x4 c) {
  return __builtin_amdgcn_mfma_f32_16x16x32_bf16(a, b, c, 0, 0, 0);
}
static __device__ __forceinline__ f32x4 mfma_f16(f16x8 a, f16x8 b, f32x4 c) {
  return __builtin_amdgcn_mfma_f32_16x16x32_f16(a, b, c, 0, 0, 0);
}

// async 16B/lane global->LDS DMA; lds dest = uniform base + lane*16
static __device__ __forceinline__ void async_ld16(const void* g, void* l) {
  __builtin_amdgcn_global_load_lds(
      (const __attribute__((address_space(1))) void*)g,
      (__attribute__((address_space(3))) void*)l, 16, 0, 0);
}

// ---------------- fused prep: weight/pos transpose (bid<272) + q/k/v fp32->bf16 conv
__global__ __launch_bounds__(256) void prep_all(
    const float* __restrict__ query, const float* __restrict__ key,
    const float* __restrict__ value,
    const float* __restrict__ Wq, const float* __restrict__ Wk,
    const float* __restrict__ Wv, const float* __restrict__ Wo,
    const float* __restrict__ pos,
    unsigned short* __restrict__ qX, unsigned short* __restrict__ kX,
    unsigned short* __restrict__ vX,
    unsigned short* __restrict__ WTq, unsigned short* __restrict__ WTk,
    unsigned short* __restrict__ WTv, unsigned short* __restrict__ WTo,
    unsigned short* __restrict__ posT) {
  __shared__ float tile[64][65];
  const int bid = blockIdx.x;
  const int tid = threadIdx.x;
  if (bid >= 272) {
    const int rem = bid - 272;
    const float* src; unsigned short* dst; int off;
    if (rem < 2048)      { src = query; dst = qX; off = rem; }
    else if (rem < 6144) { src = key;   dst = kX; off = rem - 2048; }
    else                 { src = value; dst = vX; off = rem - 6144; }
    const int idx = off * 2048 + tid * 8;
    const f32x4 f0 = *(const f32x4*)(src + idx);
    const f32x4 f1 = *(const f32x4*)(src + idx + 4);
    ushort8 h;
    h[0] = f2bf(f0[0]); h[1] = f2bf(f0[1]); h[2] = f2bf(f0[2]); h[3] = f2bf(f0[3]);
    h[4] = f2bf(f1[0]); h[5] = f2bf(f1[1]); h[6] = f2bf(f1[2]); h[7] = f2bf(f1[3]);
    *(ushort8*)(dst + idx) = h;
    return;
  }
  const float* src; unsigned short* dst;
  int src_stride, dst_stride, i0, o0;
  if (bid < 256) {
    const int w = bid >> 6, t = bid & 63;
    src = (w == 0) ? Wq : (w == 1) ? Wk : (w == 2) ? Wv : Wo;
    dst = (w == 0) ? WTq : (w == 1) ? WTk : (w == 2) ? WTv : WTo;
    src_stride = Hq; dst_stride = Hq;
    i0 = (t >> 3) * 64; o0 = (t & 7) * 64;
  } else {
    const int t = bid - 256;
    src = pos; dst = posT;
    src_stride = SPANq; dst_stride = Dq;
    i0 = 0; o0 = t * 64;
  }
  for (int e = tid; e < 4096; e += 256) {
    const int r = e >> 6, c = e & 63;
    tile[r][c] = src[(size_t)(i0 + r) * src_stride + o0 + c];
  }
  __syncthreads();
  for (int e = tid; e < 4096; e += 256) {
    const int r = e >> 6, c = e & 63;
    dst[(size_t)(o0 + r) * dst_stride + i0 + c] = f2bf(tile[c][r]);
  }
}

// ---------------- shared GEMM body: 128x128 tile, BK=64, swizzled DMA staging
// C[r][c] = sum_k Xb[r][k] * WT[c][k]
// mode 0: -> outb[(b*8+head)*T + t][d]  bf16
// mode 2: -> vT[(b*8+head)*64 + d][t]   f16 (LDS-transposed epilogue)
// mode 3: -> outf fp32 row-major
static __device__ __forceinline__ void gemm_body(
    const unsigned short* __restrict__ Xb, const unsigned short* __restrict__ WT,
    unsigned short* __restrict__ outb, _Float16* __restrict__ outv,
    float* __restrict__ outf, int mode, int tshift, int bx, int by,
    unsigned short* sh) {
  unsigned short* As = sh;               // [128][64] unpadded, swizzled
  unsigned short* Bs = sh + 8192;
  const int tid = threadIdx.x;
  const int wave = tid >> 6, lane = tid & 63;
  const int q = lane >> 4, l16 = lane & 15;
  const int wy = wave >> 1, wx = wave & 1;
  const size_t m0 = (size_t)bx * 128;
  const int n0 = by * 128;
  const int dsub = lane >> 3;
  const int dswz = (lane & 7) ^ dsub;

  f32x4 acc[4][4] = {};

  for (int k0 = 0; k0 < Hq; k0 += 64) {
    __syncthreads();
#pragma unroll
    for (int i = 0; i < 4; i++) {
      const int s = wave * 4 + i;
      const int r = s * 8 + dsub;
      async_ld16(Xb + (m0 + r) * Hq + k0 + dswz * 8, As + s * 512);
      async_ld16(WT + (size_t)(n0 + r) * Hq + k0 + dswz * 8, Bs + s * 512);
    }
    __syncthreads();
#pragma unroll
    for (int h = 0; h < 2; h++) {
      bf16x8 af[4], bg[4];
#pragma unroll
      for (int mt = 0; mt < 4; mt++) {
        const int R = wy * 64 + mt * 16 + l16;
        af[mt] = *(const bf16x8*)(As + R * 64 + (((h * 4 + q) ^ (l16 & 7)) * 8));
      }
#pragma unroll
      for (int nt = 0; nt < 4; nt++) {
        const int R = wx * 64 + nt * 16 + l16;
        bg[nt] = *(const bf16x8*)(Bs + R * 64 + (((h * 4 + q) ^ (l16 & 7)) * 8));
      }
#pragma unroll
      for (int mt = 0; mt < 4; mt++)
#pragma unroll
        for (int nt = 0; nt < 4; nt++)
          acc[mt][nt] = mfma_bf16(af[mt], bg[nt], acc[mt][nt]);
    }
  }

  if (mode == 2) {
    __syncthreads();
    _Float16* tr = (_Float16*)sh + wave * 4608;  // [64][72]
#pragma unroll
    for (int nt = 0; nt < 4; nt++)
#pragma unroll
      for (int mt = 0; mt < 4; mt++)
#pragma unroll
        for (int r = 0; r < 4; r++)
          tr[(nt * 16 + l16) * 72 + mt * 16 + q * 4 + r] = (_Float16)acc[mt][nt][r];
    const int head = by * 2 + wx;
    const int mrow0 = (int)m0 + wy * 64;
    const int Tlen = 1 << tshift;
    const int b = mrow0 >> tshift, t0 = mrow0 & (Tlen - 1);
#pragma unroll
    for (int it = 0; it < 8; it++) {
      const int dl = it * 8 + (lane >> 3), tl = (lane & 7) * 8;
      const f16x8 v = *(const f16x8*)(tr + dl * 72 + tl);
      *(f16x8*)(outv + ((size_t)((b * 8 + head) * 64 + dl)) * Tlen + t0 + tl) = v;
    }
    return;
  }

  const int Tlen = 1 << tshift;
#pragma unroll
  for (int mt = 0; mt < 4; mt++) {
#pragma unroll
    for (int nt = 0; nt < 4; nt++) {
      const int c = n0 + wx * 64 + nt * 16 + l16;
#pragma unroll
      for (int r = 0; r < 4; r++) {
        const int m = (int)m0 + wy * 64 + mt * 16 + q * 4 + r;
        const float val = acc[mt][nt][r];
        if (mode == 3) {
          outf[(size_t)m * Hq + c] = val;
        } else {
          const int b = m >> tshift, t = m & (Tlen - 1);
          const int head = c >> 6, d = c & 63;
          outb[(((size_t)(b * 8 + head) << tshift) + t) * 64 + d] = f2bf(val);
        }
      }
    }
  }
}

// fused q/k/v projection GEMMs in one launch (1280 blocks)
__global__ __launch_bounds__(256, 4) void gemm_qkv(
    const unsigned short* __restrict__ qX, const unsigned short* __restrict__ kX,
    const unsigned short* __restrict__ vX,
    const unsigned short* __restrict__ WTq, const unsigned short* __restrict__ WTk,
    const unsigned short* __restrict__ WTv,
    unsigned short* __restrict__ qb, unsigned short* __restrict__ kbuf,
    _Float16* __restrict__ vTb) {
  __shared__ unsigned short sh[18432];
  const int bid = blockIdx.x;
  if (bid < 256) {
    gemm_body(qX, WTq, qb, nullptr, nullptr, 0, 10, bid & 63, bid >> 6, sh);
  } else if (bid < 768) {
    const int b2 = bid - 256;
    gemm_body(kX, WTk, kbuf, nullptr, nullptr, 0, 11, b2 & 127, b2 >> 7, sh);
  } else {
    const int b2 = bid - 768;
    gemm_body(vX, WTv, nullptr, vTb, nullptr, 2, 11, b2 & 127, b2 >> 7, sh);
  }
}

// output projection GEMM
__global__ __launch_bounds__(256, 4) void gemm_out(
    const unsigned short* __restrict__ ctx, const unsigned short* __restrict__ WTo,
    float* __restrict__ out) {
  __shared__ unsigned short sh[18432];
  const int bid = blockIdx.x;
  gemm_body(ctx, WTo, nullptr, nullptr, out, 3, 10, bid & 63, bid >> 6, sh);
}

// ---------------- banded attention: XCD-swizzled, pipelined DMA
// block = 64 queries x one head; wave owns 16 queries; lane owns row m=lane&15.
__global__ __launch_bounds__(256, 2) void attn4(
    const unsigned short* __restrict__ qb, const unsigned short* __restrict__ kglob,
    const _Float16* __restrict__ vT, const unsigned short* __restrict__ posT,
    unsigned short* __restrict__ ctx) {
  __shared__ unsigned short Kt[12288];           // K tile: 192 rows x 64 d (swizzled)
  __shared__ unsigned short PosR[4 * 16 * PR2];  // pos-skew rows (wave-private)
  __shared__ unsigned short Prow[4 * 16 * PR2];  // P rows (wave-private)

  const int tid = threadIdx.x;
  const int wave = tid >> 6, lane = tid & 63;
  const int q = lane >> 4, l16 = lane & 15;
  const int bid = blockIdx.x;
  // XCD swizzle: all 16 m-tiles of a head share bid&7 -> same XCD, dispatched
  // within a 128-block window -> K/V band stays L2-resident.
  const int n = (bid & 7) * 8 + (bid >> 7);
  const int mtile = (bid >> 3) & 15;
  const int m0 = mtile * 64;
  const int m0w = m0 + wave * 16;
  const int dsub = lane >> 3;
  const int dswz = (lane & 7) ^ dsub;

  unsigned short* prow = Prow + (wave * 16 + l16) * PR2;
  unsigned short* posr = PosR + (wave * 16 + l16) * PR2;

  // Q fragments (B-operand): col m = l16, k = q*8+j over d
  const unsigned short* qbase = qb + ((size_t)n * Mq + m0w + l16) * Dq;
  const bf16x8 qf0 = *(const bf16x8*)(qbase + q * 8);
  const bf16x8 qf1 = *(const bf16x8*)(qbase + 32 + q * 8);

  const unsigned short* kbn = kglob + (size_t)n * MKq * Dq;
  const _Float16* vbn = vT + (size_t)n * Dq * MKq;

  f32x4 O[4] = {};
  float zrow = 0.f, mrow = -1e30f;

  // ---- prologue: DMA K(0); pos logits for chunk 0 -> PosR; drain
#pragma unroll
  for (int i = 0; i < 6; i++) {
    const int s = wave + 4 * i;
    const int r = s * 8 + dsub;
    async_ld16(kbn + (size_t)(m0 + r) * Dq + dswz * 8, Kt + s * 512);
  }
  {
    bf16x8 pf[8][2];
#pragma unroll
    for (int t = 0; t < 8; t++) {
      const unsigned short* pp = posT + (size_t)(t * 16 + l16) * Dq + q * 8;
      pf[t][0] = *(const bf16x8*)pp;
      pf[t][1] = *(const bf16x8*)(pp + 32);
    }
#pragma unroll
    for (int t = 0; t < 8; t++) {
      f32x4 b = {};
      b = mfma_bf16(pf[t][0], qf0, b);
      b = mfma_bf16(pf[t][1], qf1, b);
      const int cw = 16 + t * 16 + 4 * q + l16;
      posr[cw + 0] = f2bf(b[0]);
      posr[cw + 1] = f2bf(b[1]);
      posr[cw + 2] = f2bf(b[2]);
      posr[cw + 3] = f2bf(b[3]);
    }
  }
  __syncthreads();

  for (int c = 0; c < 8; c++) {
    const int j00 = m0w + c * 128;

    // --- ctx logits from Kt + skewed pos readback + band masks
    f32x4 S[9];
#pragma unroll
    for (int t = 0; t < 9; t++) {
      const int rl = wave * 16 + t * 16 + l16;
      const int ch = (q ^ (l16 & 7)) * 8;
      const bf16x8 k0 = *(const bf16x8*)(Kt + rl * 64 + ch);
      const bf16x8 k1 = *(const bf16x8*)(Kt + rl * 64 + (ch ^ 32));
      f32x4 a = {};
      a = mfma_bf16(k0, qf0, a);
      a = mfma_bf16(k1, qf1, a);
      const uint2v pv = *(const uint2v*)(posr + 16 + t * 16 + 4 * q);
      a[0] += __uint_as_float(pv.x << 16);
      a[1] += __uint_as_float(pv.x & 0xffff0000u);
      a[2] += __uint_as_float(pv.y << 16);
      a[3] += __uint_as_float(pv.y & 0xffff0000u);
      S[t] = a;
    }
#pragma unroll
    for (int r = 0; r < 4; r++) {
      if (4 * q + r < l16) S[0][r] = -1e30f;
      if (4 * q + r >= l16) S[8][r] = -1e30f;
    }

    if (c < 7) {
      __syncthreads();  // all waves done reading Kt(c)
      // --- DMA K(c+1)
      const int jb1 = m0 + (c + 1) * 128;
#pragma unroll
      for (int i = 0; i < 6; i++) {
        const int s = wave + 4 * i;
        const int r = s * 8 + dsub;
        async_ld16(kbn + (size_t)(jb1 + r) * Dq + dswz * 8, Kt + s * 512);
      }
      // --- pos logits for chunk c+1 (fills DMA drain window; pos is L2-hot)
      const int sb1 = (c + 1) * 128;
      bf16x8 pf[8][2];
#pragma unroll
      for (int t = 0; t < 8; t++) {
        const unsigned short* pp = posT + (size_t)(sb1 + t * 16 + l16) * Dq + q * 8;
        pf[t][0] = *(const bf16x8*)pp;
        pf[t][1] = *(const bf16x8*)(pp + 32);
      }
#pragma unroll
      for (int t = 0; t < 8; t++) {
        f32x4 b = {};
        b = mfma_bf16(pf[t][0], qf0, b);
        b = mfma_bf16(pf[t][1], qf1, b);
        const int cw = 16 + t * 16 + 4 * q + l16;
        posr[cw + 0] = f2bf(b[0]);
        posr[cw + 1] = f2bf(b[1]);
        posr[cw + 2] = f2bf(b[2]);
        posr[cw + 3] = f2bf(b[3]);
      }
    }

    // --- online softmax in registers
    float mx = -1e30f;
#pragma unroll
    for (int t = 0; t < 9; t++)
      mx = fmaxf(mx, fmaxf(fmaxf(S[t][0], S[t][1]), fmaxf(S[t][2], S[t][3])));
    mx = fmaxf(mx, __shfl_xor(mx, 16, 64));
    mx = fmaxf(mx, __shfl_xor(mx, 32, 64));
    const float m_new = fmaxf(mrow, mx);
    const float alpha = __expf((mrow - m_new) * 0.125f);
    float zs = 0.f;
#pragma unroll
    for (int t = 0; t < 9; t++) {
#pragma unroll
      for (int r = 0; r < 4; r++) {
        const float e = __expf((S[t][r] - m_new) * 0.125f);
        S[t][r] = e; zs += e;
      }
    }
    zs += __shfl_xor(zs, 16, 64);
    zs += __shfl_xor(zs, 32, 64);
    zrow = zrow * alpha + zs;
    mrow = m_new;
#pragma unroll
    for (int dt = 0; dt < 4; dt++) O[dt] *= alpha;

    // --- P -> LDS f16 at [m][j_local]; zero tail [144,160)
#pragma unroll
    for (int t = 0; t < 9; t++) {
      *(unsigned*)(prow + t * 16 + 4 * q) = pk_f16(S[t][0], S[t][1]);
      *(unsigned*)(prow + t * 16 + 4 * q + 2) = pk_f16(S[t][2], S[t][3]);
    }
    *(unsigned*)(prow + 144 + 4 * q) = 0u;
    *(unsigned*)(prow + 144 + 4 * q + 2) = 0u;

    // --- PV: O^T += V^T . P^T  (V direct from global, L2-hot after swizzle)
    f16x8 Bf[5];
#pragma unroll
    for (int kt = 0; kt < 5; kt++)
      Bf[kt] = *(const f16x8*)(prow + kt * 32 + q * 8);
    f16x8 Vv[5][4];
#pragma unroll
    for (int kt = 0; kt < 5; kt++) {
      int j = j00 + kt * 32 + q * 8;
      if (j > MKq - 8) j = MKq - 8;  // clamped cols have P==0
#pragma unroll
      for (int dt = 0; dt < 4; dt++)
        Vv[kt][dt] = *(const f16x8*)(vbn + (size_t)(dt * 16 + l16) * MKq + j);
    }
#pragma unroll
    for (int kt = 0; kt < 5; kt++)
#pragma unroll
      for (int dt = 0; dt < 4; dt++)
        O[dt] = mfma_f16(Vv[kt][dt], Bf[kt], O[dt]);

    if (c < 7) __syncthreads();  // drain DMA K(c+1) before next chunk reads Kt
  }

  // epilogue: ctx[b*M + m][head*64 + d] = O/Z  (lane owns row m = l16)
  const float zi = 1.f / zrow;
  unsigned short* cp = ctx + ((size_t)(n >> 3) * Mq + m0w + l16) * Hq + (n & 7) * Dq;
#pragma unroll
  for (int dt = 0; dt < 4; dt++)
#pragma unroll
    for (int r = 0; r < 4; r++)
      cp[dt * 16 + q * 4 + r] = f2bf(O[dt][r] * zi);
}

extern "C" void kernel_launch(void* const* d_in, const int* in_sizes, int n_in,
                              void* d_out, int out_size, void* d_ws, size_t ws_size,
                              hipStream_t stream) {
  const float* query = (const float*)d_in[0];
  const float* key   = (const float*)d_in[1];
  const float* value = (const float*)d_in[2];
  const float* pos   = (const float*)d_in[3];
  const float* Wq    = (const float*)d_in[4];
  const float* Wk    = (const float*)d_in[5];
  const float* Wv    = (const float*)d_in[6];
  const float* Wo    = (const float*)d_in[7];
  float* out = (float*)d_out;

  char* w = (char*)d_ws;
  unsigned short* qX   = (unsigned short*)w; w += (size_t)Bq * Mq * Hq * 2;    // 8 MB
  unsigned short* kX   = (unsigned short*)w; w += (size_t)Bq * MKq * Hq * 2;   // 16 MB
  unsigned short* vX   = (unsigned short*)w; w += (size_t)Bq * MKq * Hq * 2;   // 16 MB
  unsigned short* qb   = (unsigned short*)w; w += (size_t)64 * Mq * Dq * 2;    // 8 MB
  unsigned short* kbuf = (unsigned short*)w; w += (size_t)64 * MKq * Dq * 2;   // 16 MB
  _Float16*       vTb  = (_Float16*)w;       w += (size_t)64 * Dq * MKq * 2;   // 16 MB
  unsigned short* posT = (unsigned short*)w; w += (size_t)SPANq * Dq * 2;      // 128 KB
  unsigned short* WTq  = (unsigned short*)w; w += (size_t)Hq * Hq * 2;
  unsigned short* WTk  = (unsigned short*)w; w += (size_t)Hq * Hq * 2;
  unsigned short* WTv  = (unsigned short*)w; w += (size_t)Hq * Hq * 2;
  unsigned short* WTo  = (unsigned short*)w; w += (size_t)Hq * Hq * 2;
  unsigned short* ctx  = (unsigned short*)w; w += (size_t)Bq * Mq * Hq * 2;    // 8 MB

  prep_all<<<10512, 256, 0, stream>>>(query, key, value, Wq, Wk, Wv, Wo, pos,
                                      qX, kX, vX, WTq, WTk, WTv, WTo, posT);
  gemm_qkv<<<1280, 256, 0, stream>>>(qX, kX, vX, WTq, WTk, WTv, qb, kbuf, vTb);
  attn4<<<1024, 256, 0, stream>>>(qb, kbuf, vTb, posT, ctx);
  gemm_out<<<256, 256, 0, stream>>>(ctx, WTo, out);
}